// Round 4
// baseline (2087.310 us; speedup 1.0000x reference)
//
#include <hip/hip_runtime.h>

typedef _Float16 f16;
typedef _Float16 half8 __attribute__((ext_vector_type(8)));
typedef _Float16 half4v __attribute__((ext_vector_type(4)));
typedef float f32x4 __attribute__((ext_vector_type(4)));

#define N_ATOMS 100000
#define N_EDGES 200000
#define N_MOLS  4096
#define D_V 133
#define D_E 14
#define D_H 512
#define KC  672        // padded K for [W_h(512); W_i(147)] and [W_o_m(512); W_o_v(133)]
#define LDA 40         // LDS A-tile row stride (f16 elems): 80 B rows

// ---- weight build: Wt[n][k] f16 transposed, from stacked f32 W1[r1][512], W2[r2][512]
__global__ void wt_build(const float* __restrict__ W1, int r1,
                         const float* __restrict__ W2, int r2,
                         f16* __restrict__ Wt) {
    int gid = blockIdx.x * blockDim.x + threadIdx.x;
    if (gid >= D_H * KC) return;
    int n = gid / KC;
    int k = gid - n * KC;
    float x = 0.f;
    if (k < r1) x = W1[k * D_H + n];
    else if (k < r1 + r2) x = W2[(k - r1) * D_H + n];
    Wt[gid] = (f16)x;
}

// ---- CSR build over edge_dst
__global__ void csr_hist(const int* __restrict__ edst, int* __restrict__ cnt) {
    int e = blockIdx.x * blockDim.x + threadIdx.x;
    if (e < N_EDGES) atomicAdd(&cnt[edst[e]], 1);
}

__global__ __launch_bounds__(1024) void csr_scan(const int* __restrict__ cnt,
                                                 int* __restrict__ off, int* __restrict__ pos) {
    __shared__ int sums[1024];
    const int tid = threadIdx.x;
    const int lo = tid * 98;
    const int hi = min(lo + 98, N_ATOMS);
    int s = 0;
    for (int i = lo; i < hi; ++i) s += cnt[i];
    sums[tid] = s;
    __syncthreads();
    for (int d = 1; d < 1024; d <<= 1) {
        int v = (tid >= d) ? sums[tid - d] : 0;
        __syncthreads();
        sums[tid] += v;
        __syncthreads();
    }
    int run = sums[tid] - s;  // exclusive base
    for (int i = lo; i < hi; ++i) { off[i] = run; pos[i] = run; run += cnt[i]; }
    if (tid == 1023) off[N_ATOMS] = run;
}

__global__ void csr_scatter(const int* __restrict__ edst, int* __restrict__ pos,
                            int* __restrict__ eid) {
    int e = blockIdx.x * blockDim.x + threadIdx.x;
    if (e < N_EDGES) {
        int idx = atomicAdd(&pos[edst[e]], 1);
        eid[idx] = e;
    }
}

// ---- node message sum via CSR gather -> block-scaled int8
//      Mn[n,c] = sum_{e: dst(e)=n} H[e,c]; q = rn(Mn/s), s = max|Mn| over 32-col block / 127
__global__ __launch_bounds__(512) void seg_csr(
    const f16* __restrict__ H, const int* __restrict__ off, const int* __restrict__ eid,
    unsigned int* __restrict__ MnQ32, float* __restrict__ Msc)
{
    const int n = blockIdx.x * 8 + (threadIdx.x >> 6);
    const int lane = threadIdx.x & 63;
    const int j0 = off[n], j1 = off[n + 1];
    float acc[8];
    #pragma unroll
    for (int k = 0; k < 8; ++k) acc[k] = 0.f;
    for (int j = j0; j < j1; ++j) {
        const int e = eid[j];
        const half8 h = *reinterpret_cast<const half8*>(&H[e * D_H + lane * 8]);
        #pragma unroll
        for (int k = 0; k < 8; ++k) acc[k] += (float)h[k];
    }
    // block max over 32 cols = 4 consecutive lanes (lane covers cols lane*8..lane*8+7)
    float m = 0.f;
    #pragma unroll
    for (int k = 0; k < 8; ++k) m = fmaxf(m, fabsf(acc[k]));
    m = fmaxf(m, __shfl_xor(m, 1));
    m = fmaxf(m, __shfl_xor(m, 2));
    m = fmaxf(m, 1e-20f);
    const float s = m * (1.f / 127.f);
    const float inv_s = 127.f / m;
    if ((lane & 3) == 0) Msc[n * 16 + (lane >> 2)] = s;
    int q[8];
    #pragma unroll
    for (int k = 0; k < 8; ++k) q[k] = __float2int_rn(acc[k] * inv_s);
    uint2 o;
    o.x = (q[0] & 0xff) | ((q[1] & 0xff) << 8) | ((q[2] & 0xff) << 16) | ((unsigned)(q[3] & 0xff) << 24);
    o.y = (q[4] & 0xff) | ((q[5] & 0xff) << 8) | ((q[6] & 0xff) << 16) | ((unsigned)(q[7] & 0xff) << 24);
    *reinterpret_cast<uint2*>(&MnQ32[n * 128 + lane * 2]) = o;
}

// ---- fused message-passing GEMM (in-place on Ha):
//   Ha[e] = relu( [deq(Mn)[src]-Ha[rev] (512) ; V[src] (133) ; E[e] (14)] @ Wt )
// ks_begin=16 -> init pass (M region skipped; Mn/Ha not read)
__global__ __launch_bounds__(512) void gemm_pass(
    const float* __restrict__ V, const float* __restrict__ E,
    const int* __restrict__ esrc, const char* __restrict__ MnQ,
    const float* __restrict__ Msc,
    f16* __restrict__ Ha, const f16* __restrict__ Wt, int ks_begin)
{
    __shared__ __align__(16) f16 Al[64 * LDA];
    const int tid = threadIdx.x;
    const int rowblk = blockIdx.x << 6;
    const int srow = tid >> 3;
    const int skk  = (tid & 7) << 2;
    const int e_s  = rowblk + srow;
    const int sv   = esrc[e_s];
    const int rev  = e_s ^ 1;
    const int lane = tid & 63;
    const int quad = lane >> 4;
    const int m16  = lane & 15;
    const int colbase = (tid >> 6) << 6;

    f32x4 acc[4][4];
    #pragma unroll
    for (int a = 0; a < 4; ++a)
    #pragma unroll
    for (int b = 0; b < 4; ++b)
    #pragma unroll
    for (int r = 0; r < 4; ++r) acc[a][b][r] = 0.f;

    for (int ks = ks_begin; ks < KC / 32; ++ks) {
        const int k0 = ks << 5;
        __syncthreads();
        {
            half4v w;
            if (k0 < D_H) {  // M region: dequant int8 Mn[src], subtract f16 Ha[rev]
                const char4 qc = *reinterpret_cast<const char4*>(&MnQ[sv * D_H + k0 + skk]);
                const float s = Msc[sv * 16 + ((k0 + skk) >> 5)];
                const half4v h4 = *reinterpret_cast<const half4v*>(&Ha[rev * D_H + k0 + skk]);
                w[0] = (f16)((float)qc.x * s - (float)h4[0]);
                w[1] = (f16)((float)qc.y * s - (float)h4[1]);
                w[2] = (f16)((float)qc.z * s - (float)h4[2]);
                w[3] = (f16)((float)qc.w * s - (float)h4[3]);
            } else {         // [V ; E ; pad] region
                #pragma unroll
                for (int j = 0; j < 4; ++j) {
                    const int kk = k0 + skk + j - D_H;
                    float x = 0.f;
                    if (kk < D_V) x = V[sv * D_V + kk];
                    else if (kk < D_V + D_E) x = E[e_s * D_E + (kk - D_V)];
                    w[j] = (f16)x;
                }
            }
            *reinterpret_cast<half4v*>(&Al[srow * LDA + skk]) = w;
        }
        __syncthreads();
        half8 af[4];
        #pragma unroll
        for (int rt = 0; rt < 4; ++rt)
            af[rt] = *reinterpret_cast<const half8*>(&Al[(rt * 16 + m16) * LDA + quad * 8]);
        #pragma unroll
        for (int ct = 0; ct < 4; ++ct) {
            const int n = colbase + ct * 16 + m16;
            const half8 bf = *reinterpret_cast<const half8*>(&Wt[n * KC + k0 + quad * 8]);
            #pragma unroll
            for (int rt = 0; rt < 4; ++rt)
                acc[rt][ct] = __builtin_amdgcn_mfma_f32_16x16x32_f16(af[rt], bf, acc[rt][ct], 0, 0, 0);
        }
    }
    // epilogue: in-place overwrite is safe (all Ha[rev] reads are in-block, barrier-ordered)
    #pragma unroll
    for (int rt = 0; rt < 4; ++rt)
    #pragma unroll
    for (int ct = 0; ct < 4; ++ct)
    #pragma unroll
    for (int r = 0; r < 4; ++r) {
        const int row = rowblk + rt * 16 + quad * 4 + r;
        const int col = colbase + ct * 16 + m16;
        Ha[row * D_H + col] = (f16)fmaxf(acc[rt][ct][r], 0.f);
    }
}

// ---- output GEMM with EXACT fused CSR aggregation:
//   M_v[a] = sum_{e: dst(e)=a} Ha[e]  (f32, computed per K-tile in staging)
//   h = relu([M_v(512); V(133)] @ WtO + b_o); molsum[batch[a]] += h
__global__ __launch_bounds__(512) void gemm_out(
    const float* __restrict__ V, const f16* __restrict__ Ha,
    const int* __restrict__ off, const int* __restrict__ eid,
    const int* __restrict__ batch, const float* __restrict__ bo,
    const f16* __restrict__ Wt, float* __restrict__ molsum)
{
    __shared__ __align__(16) f16 Al[64 * LDA];
    __shared__ int batch_s[64];
    __shared__ float bo_s[D_H];
    const int tid = threadIdx.x;
    const int rowblk = blockIdx.x << 6;
    if (tid < 64) batch_s[tid] = batch[min(rowblk + tid, N_ATOMS - 1)];
    bo_s[tid] = bo[tid];
    const int srow = tid >> 3;
    const int skk  = (tid & 7) << 2;
    const int arow = min(rowblk + srow, N_ATOMS - 1);
    const int j0 = off[arow], j1 = off[arow + 1];
    const int lane = tid & 63;
    const int quad = lane >> 4;
    const int m16  = lane & 15;
    const int colbase = (tid >> 6) << 6;

    f32x4 acc[4][4];
    #pragma unroll
    for (int a = 0; a < 4; ++a)
    #pragma unroll
    for (int b = 0; b < 4; ++b)
    #pragma unroll
    for (int r = 0; r < 4; ++r) acc[a][b][r] = 0.f;

    for (int ks = 0; ks < KC / 32; ++ks) {
        const int k0 = ks << 5;
        __syncthreads();
        {
            half4v w;
            if (k0 < D_H) {  // M_v region: exact CSR gather, f32 accumulate
                float a0 = 0.f, a1 = 0.f, a2 = 0.f, a3 = 0.f;
                for (int j = j0; j < j1; ++j) {
                    const int e = eid[j];
                    const half4v h4 = *reinterpret_cast<const half4v*>(&Ha[e * D_H + k0 + skk]);
                    a0 += (float)h4[0]; a1 += (float)h4[1];
                    a2 += (float)h4[2]; a3 += (float)h4[3];
                }
                w[0] = (f16)a0; w[1] = (f16)a1; w[2] = (f16)a2; w[3] = (f16)a3;
            } else {         // [V ; pad]
                #pragma unroll
                for (int j = 0; j < 4; ++j) {
                    const int kk = k0 + skk + j - D_H;
                    w[j] = (kk < D_V) ? (f16)V[arow * D_V + kk] : (f16)0.f;
                }
            }
            *reinterpret_cast<half4v*>(&Al[srow * LDA + skk]) = w;
        }
        __syncthreads();
        half8 af[4];
        #pragma unroll
        for (int rt = 0; rt < 4; ++rt)
            af[rt] = *reinterpret_cast<const half8*>(&Al[(rt * 16 + m16) * LDA + quad * 8]);
        #pragma unroll
        for (int ct = 0; ct < 4; ++ct) {
            const int n = colbase + ct * 16 + m16;
            const half8 bf = *reinterpret_cast<const half8*>(&Wt[n * KC + k0 + quad * 8]);
            #pragma unroll
            for (int rt = 0; rt < 4; ++rt)
                acc[rt][ct] = __builtin_amdgcn_mfma_f32_16x16x32_f16(af[rt], bf, acc[rt][ct], 0, 0, 0);
        }
    }
    #pragma unroll
    for (int rt = 0; rt < 4; ++rt)
    #pragma unroll
    for (int ct = 0; ct < 4; ++ct)
    #pragma unroll
    for (int r = 0; r < 4; ++r) {
        const int row = rowblk + rt * 16 + quad * 4 + r;
        if (row < N_ATOMS) {
            const int col = colbase + ct * 16 + m16;
            const float x = fmaxf(acc[rt][ct][r] + bo_s[col], 0.f);
            unsafeAtomicAdd(&molsum[batch_s[rt * 16 + quad * 4 + r] * D_H + col], x);
        }
    }
}

__global__ void mol_count(const int* __restrict__ batch, float* __restrict__ cnt) {
    int a = blockIdx.x * blockDim.x + threadIdx.x;
    if (a < N_ATOMS) unsafeAtomicAdd(&cnt[batch[a]], 1.f);
}

__global__ __launch_bounds__(256) void bn_stats(
    const float* __restrict__ molsum, const float* __restrict__ cnt,
    const float* __restrict__ gamma, const float* __restrict__ beta,
    float* __restrict__ An, float* __restrict__ Bn)
{
    const int n = blockIdx.x;
    const int tid = threadIdx.x;
    float s = 0.f, s2 = 0.f;
    for (int m = tid; m < N_MOLS; m += 256) {
        float h = molsum[m * D_H + n] / fmaxf(cnt[m], 1.f);
        s += h; s2 += h * h;
    }
    for (int off = 32; off > 0; off >>= 1) {
        s  += __shfl_down(s, off);
        s2 += __shfl_down(s2, off);
    }
    __shared__ float sh[8];
    const int wave = tid >> 6, lane = tid & 63;
    if (lane == 0) { sh[wave] = s; sh[4 + wave] = s2; }
    __syncthreads();
    if (tid == 0) {
        float S  = sh[0] + sh[1] + sh[2] + sh[3];
        float S2 = sh[4] + sh[5] + sh[6] + sh[7];
        float mu = S / (float)N_MOLS;
        float var = fmaxf(S2 / (float)N_MOLS - mu * mu, 0.f);
        float sc = rsqrtf(var + 1e-5f) * gamma[n];
        An[n] = sc;
        Bn[n] = beta[n] - mu * sc;
    }
}

// in-place: out[gid] depends only on molsum[gid] (same index), An/Bn
__global__ void bn_apply(const float* __restrict__ molsum, const float* __restrict__ cnt,
                         const float* __restrict__ An, const float* __restrict__ Bn,
                         float* __restrict__ out)
{
    int gid = blockIdx.x * blockDim.x + threadIdx.x;
    int m = gid >> 9, n = gid & 511;
    float h = molsum[gid] / fmaxf(cnt[m], 1.f);
    out[gid] = h * An[n] + Bn[n];
}

extern "C" void kernel_launch(void* const* d_in, const int* in_sizes, int n_in,
                              void* d_out, int out_size, void* d_ws, size_t ws_size,
                              hipStream_t stream)
{
    (void)in_sizes; (void)n_in; (void)out_size; (void)ws_size;
    const float* V     = (const float*)d_in[0];
    const float* E     = (const float*)d_in[1];
    const int*   esrc  = (const int*)d_in[2];
    const int*   edst  = (const int*)d_in[3];
    const int*   batch = (const int*)d_in[4];
    const float* Wi    = (const float*)d_in[5];
    const float* Wh    = (const float*)d_in[6];
    const float* Wo    = (const float*)d_in[7];
    const float* bo    = (const float*)d_in[8];
    const float* gam   = (const float*)d_in[9];
    const float* bet   = (const float*)d_in[10];
    float* out = (float*)d_out;

    // workspace layout — total 265,396,864 B (~253.1 MiB)
    char* ws = (char*)d_ws;
    f16*   WtC  = (f16*)(ws + 0);                   //    688,128 B
    f16*   WtO  = (f16*)(ws + 688128);              //    688,128 B
    int*   off  = (int*)(ws + 1376256);             //    400,128 B (N_ATOMS+1 ints)
    int*   eid  = (int*)(ws + 1776384);             //    800,000 B
    int*   cnt  = (int*)(ws + 2576384);             //    400,000 B (also 'pos' cursor)
    float* Mc   = (float*)(ws + 2976384);           //     16,384 B
    float* An   = (float*)(ws + 2992768);           //      2,048 B
    float* Bn   = (float*)(ws + 2994816);           //      2,048 B
    f16*   Ha   = (f16*)(ws + 2996864);             // 204,800,000 B
    char*  MnQ  = (char*)(ws + 207796864);          //  51,200,000 B int8
    float* Msc  = (float*)(ws + 258996864);         //   6,400,000 B scales
    unsigned int* MnQ32 = (unsigned int*)MnQ;
    float* Ms = out;                                 // mol sums live in d_out (8,388,608 B)

    // weights
    wt_build<<<(D_H * KC + 255) / 256, 256, 0, stream>>>(Wh, D_H, Wi, D_V + D_E, WtC);
    wt_build<<<(D_H * KC + 255) / 256, 256, 0, stream>>>(Wo + D_V * D_H, D_H, Wo, D_V, WtO);

    // CSR over edge_dst (cnt doubles as scatter cursor 'pos')
    hipMemsetAsync(cnt, 0, 400000, stream);
    csr_hist<<<(N_EDGES + 511) / 512, 512, 0, stream>>>(edst, cnt);
    csr_scan<<<1, 1024, 0, stream>>>(cnt, off, cnt);
    csr_scatter<<<(N_EDGES + 511) / 512, 512, 0, stream>>>(edst, cnt, eid);

    // init: H = relu([V;E] @ W_i)
    gemm_pass<<<N_EDGES / 64, 512, 0, stream>>>(V, E, esrc, MnQ, Msc, Ha, WtC, 16);

    // DEPTH-1 = 2 message-passing iterations (int8 block-scaled Mn)
    for (int it = 0; it < 2; ++it) {
        seg_csr<<<N_ATOMS / 8, 512, 0, stream>>>(Ha, off, eid, MnQ32, Msc);
        gemm_pass<<<N_EDGES / 64, 512, 0, stream>>>(V, E, esrc, MnQ, Msc, Ha, WtC, 0);
    }

    // output GEMM: exact fused CSR aggregation + mol-sum (into d_out), then BatchNorm
    hipMemsetAsync(Ms, 0, (size_t)N_MOLS * D_H * 4, stream);
    hipMemsetAsync(Mc, 0, 16384, stream);
    mol_count<<<(N_ATOMS + 255) / 256, 256, 0, stream>>>(batch, Mc);
    gemm_out<<<(N_ATOMS + 63) / 64, 512, 0, stream>>>(V, Ha, off, eid, batch, bo, WtO, Ms);

    bn_stats<<<D_H, 256, 0, stream>>>(Ms, Mc, gam, bet, An, Bn);
    bn_apply<<<(N_MOLS * D_H) / 256, 256, 0, stream>>>(Ms, Mc, An, Bn, out);
}

// Round 5
// 2011.393 us; speedup vs baseline: 1.0377x; 1.0377x over previous
//
#include <hip/hip_runtime.h>

typedef _Float16 f16;
typedef _Float16 half8 __attribute__((ext_vector_type(8)));
typedef _Float16 half4v __attribute__((ext_vector_type(4)));
typedef float f32x4 __attribute__((ext_vector_type(4)));

#define N_ATOMS 100000
#define N_EDGES 200000
#define N_MOLS  4096
#define D_V 133
#define D_E 14
#define D_H 512
#define KC  672        // padded K for [W_h(512); W_i(147)] and [W_o_m(512); W_o_v(133)]
#define LDA 40         // LDS A-tile row stride (f16 elems): 80 B rows

// ---- weight build: Wt[n][k] f16 transposed, from stacked f32 W1[r1][512], W2[r2][512]
__global__ void wt_build(const float* __restrict__ W1, int r1,
                         const float* __restrict__ W2, int r2,
                         f16* __restrict__ Wt) {
    int gid = blockIdx.x * blockDim.x + threadIdx.x;
    if (gid >= D_H * KC) return;
    int n = gid / KC;
    int k = gid - n * KC;
    float x = 0.f;
    if (k < r1) x = W1[k * D_H + n];
    else if (k < r1 + r2) x = W2[(k - r1) * D_H + n];
    Wt[gid] = (f16)x;
}

// ---- CSR build over edge_dst
__global__ void csr_hist(const int* __restrict__ edst, int* __restrict__ cnt) {
    int e = blockIdx.x * blockDim.x + threadIdx.x;
    if (e < N_EDGES) atomicAdd(&cnt[edst[e]], 1);
}

__global__ __launch_bounds__(1024) void csr_scan(const int* __restrict__ cnt,
                                                 int* __restrict__ off, int* __restrict__ pos) {
    __shared__ int sums[1024];
    const int tid = threadIdx.x;
    const int lo = tid * 98;
    const int hi = min(lo + 98, N_ATOMS);
    int s = 0;
    for (int i = lo; i < hi; ++i) s += cnt[i];
    sums[tid] = s;
    __syncthreads();
    for (int d = 1; d < 1024; d <<= 1) {
        int v = (tid >= d) ? sums[tid - d] : 0;
        __syncthreads();
        sums[tid] += v;
        __syncthreads();
    }
    int run = sums[tid] - s;  // exclusive base
    for (int i = lo; i < hi; ++i) { off[i] = run; pos[i] = run; run += cnt[i]; }
    if (tid == 1023) off[N_ATOMS] = run;
}

__global__ void csr_scatter(const int* __restrict__ edst, int* __restrict__ pos,
                            int* __restrict__ eid) {
    int e = blockIdx.x * blockDim.x + threadIdx.x;
    if (e < N_EDGES) {
        int idx = atomicAdd(&pos[edst[e]], 1);
        eid[idx] = e;
    }
}

// ---- node message sum via CSR gather -> block-scaled int8
//      Mn[n,c] = sum_{e: dst(e)=n} H[e,c]; q = rn(Mn/s), s = max|Mn| over 32-col block / 127
__global__ __launch_bounds__(512) void seg_csr(
    const f16* __restrict__ H, const int* __restrict__ off, const int* __restrict__ eid,
    unsigned int* __restrict__ MnQ32, float* __restrict__ Msc)
{
    const int n = blockIdx.x * 8 + (threadIdx.x >> 6);
    const int lane = threadIdx.x & 63;
    const int j0 = off[n], j1 = off[n + 1];
    float acc[8];
    #pragma unroll
    for (int k = 0; k < 8; ++k) acc[k] = 0.f;
    for (int j = j0; j < j1; ++j) {
        const int e = eid[j];
        const half8 h = *reinterpret_cast<const half8*>(&H[e * D_H + lane * 8]);
        #pragma unroll
        for (int k = 0; k < 8; ++k) acc[k] += (float)h[k];
    }
    // block max over 32 cols = 4 consecutive lanes (lane covers cols lane*8..lane*8+7)
    float m = 0.f;
    #pragma unroll
    for (int k = 0; k < 8; ++k) m = fmaxf(m, fabsf(acc[k]));
    m = fmaxf(m, __shfl_xor(m, 1));
    m = fmaxf(m, __shfl_xor(m, 2));
    m = fmaxf(m, 1e-20f);
    const float s = m * (1.f / 127.f);
    const float inv_s = 127.f / m;
    if ((lane & 3) == 0) Msc[n * 16 + (lane >> 2)] = s;
    int q[8];
    #pragma unroll
    for (int k = 0; k < 8; ++k) q[k] = __float2int_rn(acc[k] * inv_s);
    uint2 o;
    o.x = (q[0] & 0xff) | ((q[1] & 0xff) << 8) | ((q[2] & 0xff) << 16) | ((unsigned)(q[3] & 0xff) << 24);
    o.y = (q[4] & 0xff) | ((q[5] & 0xff) << 8) | ((q[6] & 0xff) << 16) | ((unsigned)(q[7] & 0xff) << 24);
    *reinterpret_cast<uint2*>(&MnQ32[n * 128 + lane * 2]) = o;
}

// ---- fused message-passing GEMM (in-place on Ha):
//   Ha[e] = relu( [deq(Mn)[src]-Ha[rev] (512) ; V[src] (133) ; E[e] (14)] @ Wt )
// ks_begin=16 -> init pass (M region skipped; Mn/Ha not read)
__global__ __launch_bounds__(512) void gemm_pass(
    const float* __restrict__ V, const float* __restrict__ E,
    const int* __restrict__ esrc, const char* __restrict__ MnQ,
    const float* __restrict__ Msc,
    f16* __restrict__ Ha, const f16* __restrict__ Wt, int ks_begin)
{
    __shared__ __align__(16) f16 Al[64 * LDA];
    const int tid = threadIdx.x;
    const int rowblk = blockIdx.x << 6;
    const int srow = tid >> 3;
    const int skk  = (tid & 7) << 2;
    const int e_s  = rowblk + srow;
    const int sv   = esrc[e_s];
    const int rev  = e_s ^ 1;
    const int lane = tid & 63;
    const int quad = lane >> 4;
    const int m16  = lane & 15;
    const int colbase = (tid >> 6) << 6;

    f32x4 acc[4][4];
    #pragma unroll
    for (int a = 0; a < 4; ++a)
    #pragma unroll
    for (int b = 0; b < 4; ++b)
    #pragma unroll
    for (int r = 0; r < 4; ++r) acc[a][b][r] = 0.f;

    for (int ks = ks_begin; ks < KC / 32; ++ks) {
        const int k0 = ks << 5;
        __syncthreads();
        {
            half4v w;
            if (k0 < D_H) {  // M region: dequant int8 Mn[src], subtract f16 Ha[rev]
                const char4 qc = *reinterpret_cast<const char4*>(&MnQ[sv * D_H + k0 + skk]);
                const float s = Msc[sv * 16 + ((k0 + skk) >> 5)];
                const half4v h4 = *reinterpret_cast<const half4v*>(&Ha[rev * D_H + k0 + skk]);
                w[0] = (f16)((float)qc.x * s - (float)h4[0]);
                w[1] = (f16)((float)qc.y * s - (float)h4[1]);
                w[2] = (f16)((float)qc.z * s - (float)h4[2]);
                w[3] = (f16)((float)qc.w * s - (float)h4[3]);
            } else {         // [V ; E ; pad] region
                #pragma unroll
                for (int j = 0; j < 4; ++j) {
                    const int kk = k0 + skk + j - D_H;
                    float x = 0.f;
                    if (kk < D_V) x = V[sv * D_V + kk];
                    else if (kk < D_V + D_E) x = E[e_s * D_E + (kk - D_V)];
                    w[j] = (f16)x;
                }
            }
            *reinterpret_cast<half4v*>(&Al[srow * LDA + skk]) = w;
        }
        __syncthreads();
        half8 af[4];
        #pragma unroll
        for (int rt = 0; rt < 4; ++rt)
            af[rt] = *reinterpret_cast<const half8*>(&Al[(rt * 16 + m16) * LDA + quad * 8]);
        #pragma unroll
        for (int ct = 0; ct < 4; ++ct) {
            const int n = colbase + ct * 16 + m16;
            const half8 bf = *reinterpret_cast<const half8*>(&Wt[n * KC + k0 + quad * 8]);
            #pragma unroll
            for (int rt = 0; rt < 4; ++rt)
                acc[rt][ct] = __builtin_amdgcn_mfma_f32_16x16x32_f16(af[rt], bf, acc[rt][ct], 0, 0, 0);
        }
    }
    // epilogue: in-place overwrite is safe (all Ha[rev] reads are in-block, barrier-ordered)
    #pragma unroll
    for (int rt = 0; rt < 4; ++rt)
    #pragma unroll
    for (int ct = 0; ct < 4; ++ct)
    #pragma unroll
    for (int r = 0; r < 4; ++r) {
        const int row = rowblk + rt * 16 + quad * 4 + r;
        const int col = colbase + ct * 16 + m16;
        Ha[row * D_H + col] = (f16)fmaxf(acc[rt][ct][r], 0.f);
    }
}

// ---- output GEMM (reads int8 block-scaled M_v like gemm_pass — no gather):
//   h = relu([deq(Mn)(512); V(133)] @ WtO + b_o); molsum[batch[a]] += h
__global__ __launch_bounds__(512) void gemm_out(
    const float* __restrict__ V, const char* __restrict__ MnQ,
    const float* __restrict__ Msc,
    const int* __restrict__ batch, const float* __restrict__ bo,
    const f16* __restrict__ Wt, float* __restrict__ molsum)
{
    __shared__ __align__(16) f16 Al[64 * LDA];
    __shared__ int batch_s[64];
    __shared__ float bo_s[D_H];
    const int tid = threadIdx.x;
    const int rowblk = blockIdx.x << 6;
    if (tid < 64) batch_s[tid] = batch[min(rowblk + tid, N_ATOMS - 1)];
    bo_s[tid] = bo[tid];
    const int srow = tid >> 3;
    const int skk  = (tid & 7) << 2;
    const int arow = min(rowblk + srow, N_ATOMS - 1);
    const int lane = tid & 63;
    const int quad = lane >> 4;
    const int m16  = lane & 15;
    const int colbase = (tid >> 6) << 6;

    f32x4 acc[4][4];
    #pragma unroll
    for (int a = 0; a < 4; ++a)
    #pragma unroll
    for (int b = 0; b < 4; ++b)
    #pragma unroll
    for (int r = 0; r < 4; ++r) acc[a][b][r] = 0.f;

    for (int ks = 0; ks < KC / 32; ++ks) {
        const int k0 = ks << 5;
        __syncthreads();
        {
            half4v w;
            if (k0 < D_H) {  // M_v region: dequant int8 (coalesced)
                const char4 qc = *reinterpret_cast<const char4*>(&MnQ[arow * D_H + k0 + skk]);
                const float s = Msc[arow * 16 + ((k0 + skk) >> 5)];
                w[0] = (f16)((float)qc.x * s);
                w[1] = (f16)((float)qc.y * s);
                w[2] = (f16)((float)qc.z * s);
                w[3] = (f16)((float)qc.w * s);
            } else {         // [V ; pad]
                #pragma unroll
                for (int j = 0; j < 4; ++j) {
                    const int kk = k0 + skk + j - D_H;
                    w[j] = (kk < D_V) ? (f16)V[arow * D_V + kk] : (f16)0.f;
                }
            }
            *reinterpret_cast<half4v*>(&Al[srow * LDA + skk]) = w;
        }
        __syncthreads();
        half8 af[4];
        #pragma unroll
        for (int rt = 0; rt < 4; ++rt)
            af[rt] = *reinterpret_cast<const half8*>(&Al[(rt * 16 + m16) * LDA + quad * 8]);
        #pragma unroll
        for (int ct = 0; ct < 4; ++ct) {
            const int n = colbase + ct * 16 + m16;
            const half8 bf = *reinterpret_cast<const half8*>(&Wt[n * KC + k0 + quad * 8]);
            #pragma unroll
            for (int rt = 0; rt < 4; ++rt)
                acc[rt][ct] = __builtin_amdgcn_mfma_f32_16x16x32_f16(af[rt], bf, acc[rt][ct], 0, 0, 0);
        }
    }
    #pragma unroll
    for (int rt = 0; rt < 4; ++rt)
    #pragma unroll
    for (int ct = 0; ct < 4; ++ct)
    #pragma unroll
    for (int r = 0; r < 4; ++r) {
        const int row = rowblk + rt * 16 + quad * 4 + r;
        if (row < N_ATOMS) {
            const int col = colbase + ct * 16 + m16;
            const float x = fmaxf(acc[rt][ct][r] + bo_s[col], 0.f);
            unsafeAtomicAdd(&molsum[batch_s[rt * 16 + quad * 4 + r] * D_H + col], x);
        }
    }
}

__global__ void mol_count(const int* __restrict__ batch, float* __restrict__ cnt) {
    int a = blockIdx.x * blockDim.x + threadIdx.x;
    if (a < N_ATOMS) unsafeAtomicAdd(&cnt[batch[a]], 1.f);
}

__global__ __launch_bounds__(256) void bn_stats(
    const float* __restrict__ molsum, const float* __restrict__ cnt,
    const float* __restrict__ gamma, const float* __restrict__ beta,
    float* __restrict__ An, float* __restrict__ Bn)
{
    const int n = blockIdx.x;
    const int tid = threadIdx.x;
    float s = 0.f, s2 = 0.f;
    for (int m = tid; m < N_MOLS; m += 256) {
        float h = molsum[m * D_H + n] / fmaxf(cnt[m], 1.f);
        s += h; s2 += h * h;
    }
    for (int off = 32; off > 0; off >>= 1) {
        s  += __shfl_down(s, off);
        s2 += __shfl_down(s2, off);
    }
    __shared__ float sh[8];
    const int wave = tid >> 6, lane = tid & 63;
    if (lane == 0) { sh[wave] = s; sh[4 + wave] = s2; }
    __syncthreads();
    if (tid == 0) {
        float S  = sh[0] + sh[1] + sh[2] + sh[3];
        float S2 = sh[4] + sh[5] + sh[6] + sh[7];
        float mu = S / (float)N_MOLS;
        float var = fmaxf(S2 / (float)N_MOLS - mu * mu, 0.f);
        float sc = rsqrtf(var + 1e-5f) * gamma[n];
        An[n] = sc;
        Bn[n] = beta[n] - mu * sc;
    }
}

// in-place: out[gid] depends only on molsum[gid] (same index), An/Bn
__global__ void bn_apply(const float* __restrict__ molsum, const float* __restrict__ cnt,
                         const float* __restrict__ An, const float* __restrict__ Bn,
                         float* __restrict__ out)
{
    int gid = blockIdx.x * blockDim.x + threadIdx.x;
    int m = gid >> 9, n = gid & 511;
    float h = molsum[gid] / fmaxf(cnt[m], 1.f);
    out[gid] = h * An[n] + Bn[n];
}

extern "C" void kernel_launch(void* const* d_in, const int* in_sizes, int n_in,
                              void* d_out, int out_size, void* d_ws, size_t ws_size,
                              hipStream_t stream)
{
    (void)in_sizes; (void)n_in; (void)out_size; (void)ws_size;
    const float* V     = (const float*)d_in[0];
    const float* E     = (const float*)d_in[1];
    const int*   esrc  = (const int*)d_in[2];
    const int*   edst  = (const int*)d_in[3];
    const int*   batch = (const int*)d_in[4];
    const float* Wi    = (const float*)d_in[5];
    const float* Wh    = (const float*)d_in[6];
    const float* Wo    = (const float*)d_in[7];
    const float* bo    = (const float*)d_in[8];
    const float* gam   = (const float*)d_in[9];
    const float* bet   = (const float*)d_in[10];
    float* out = (float*)d_out;

    // workspace layout — total 265,396,864 B (~253.1 MiB)
    char* ws = (char*)d_ws;
    f16*   WtC  = (f16*)(ws + 0);                   //    688,128 B
    f16*   WtO  = (f16*)(ws + 688128);              //    688,128 B
    int*   off  = (int*)(ws + 1376256);             //    400,128 B (N_ATOMS+1 ints)
    int*   eid  = (int*)(ws + 1776384);             //    800,000 B
    int*   cnt  = (int*)(ws + 2576384);             //    400,000 B (also 'pos' cursor)
    float* Mc   = (float*)(ws + 2976384);           //     16,384 B
    float* An   = (float*)(ws + 2992768);           //      2,048 B
    float* Bn   = (float*)(ws + 2994816);           //      2,048 B
    f16*   Ha   = (f16*)(ws + 2996864);             // 204,800,000 B
    char*  MnQ  = (char*)(ws + 207796864);          //  51,200,000 B int8
    float* Msc  = (float*)(ws + 258996864);         //   6,400,000 B scales
    unsigned int* MnQ32 = (unsigned int*)MnQ;
    float* Ms = out;                                 // mol sums live in d_out (8,388,608 B)

    // weights
    wt_build<<<(D_H * KC + 255) / 256, 256, 0, stream>>>(Wh, D_H, Wi, D_V + D_E, WtC);
    wt_build<<<(D_H * KC + 255) / 256, 256, 0, stream>>>(Wo + D_V * D_H, D_H, Wo, D_V, WtO);

    // CSR over edge_dst (cnt doubles as scatter cursor 'pos')
    hipMemsetAsync(cnt, 0, 400000, stream);
    csr_hist<<<(N_EDGES + 511) / 512, 512, 0, stream>>>(edst, cnt);
    csr_scan<<<1, 1024, 0, stream>>>(cnt, off, cnt);
    csr_scatter<<<(N_EDGES + 511) / 512, 512, 0, stream>>>(edst, cnt, eid);

    // init: H = relu([V;E] @ W_i)
    gemm_pass<<<N_EDGES / 64, 512, 0, stream>>>(V, E, esrc, MnQ, Msc, Ha, WtC, 16);

    // DEPTH-1 = 2 message-passing iterations (int8 block-scaled Mn)
    for (int it = 0; it < 2; ++it) {
        seg_csr<<<N_ATOMS / 8, 512, 0, stream>>>(Ha, off, eid, MnQ32, Msc);
        gemm_pass<<<N_EDGES / 64, 512, 0, stream>>>(V, E, esrc, MnQ, Msc, Ha, WtC, 0);
    }

    // final edge->node aggregation (same int8 path; gemm_out reads it coalesced)
    seg_csr<<<N_ATOMS / 8, 512, 0, stream>>>(Ha, off, eid, MnQ32, Msc);

    // output GEMM with fused mol-sum (into d_out), then BatchNorm
    hipMemsetAsync(Ms, 0, (size_t)N_MOLS * D_H * 4, stream);
    hipMemsetAsync(Mc, 0, 16384, stream);
    mol_count<<<(N_ATOMS + 255) / 256, 256, 0, stream>>>(batch, Mc);
    gemm_out<<<(N_ATOMS + 63) / 64, 512, 0, stream>>>(V, MnQ, Msc, batch, bo, WtO, Ms);

    bn_stats<<<D_H, 256, 0, stream>>>(Ms, Mc, gam, bet, An, Bn);
    bn_apply<<<(N_MOLS * D_H) / 256, 256, 0, stream>>>(Ms, Mc, An, Bn, out);
}

// Round 6
// 1876.306 us; speedup vs baseline: 1.1125x; 1.0720x over previous
//
#include <hip/hip_runtime.h>

typedef _Float16 f16;
typedef _Float16 half8 __attribute__((ext_vector_type(8)));
typedef _Float16 half4v __attribute__((ext_vector_type(4)));
typedef float f32x4 __attribute__((ext_vector_type(4)));

#define N_ATOMS 100000
#define N_EDGES 200000
#define N_MOLS  4096
#define D_V 133
#define D_E 14
#define D_H 512
#define KC  672        // padded K for [W_h(512); W_i(147)] and [W_o_m(512); W_o_v(133)]
#define LDA 40         // LDS A-tile row stride (f16 elems): 80 B rows
#define MAXML 8        // max distinct molecules per 64-row block for LDS reduction path

// ---- weight build: Wt[n][k] f16 transposed, from stacked f32 W1[r1][512], W2[r2][512]
__global__ void wt_build(const float* __restrict__ W1, int r1,
                         const float* __restrict__ W2, int r2,
                         f16* __restrict__ Wt) {
    int gid = blockIdx.x * blockDim.x + threadIdx.x;
    if (gid >= D_H * KC) return;
    int n = gid / KC;
    int k = gid - n * KC;
    float x = 0.f;
    if (k < r1) x = W1[k * D_H + n];
    else if (k < r1 + r2) x = W2[(k - r1) * D_H + n];
    Wt[gid] = (f16)x;
}

// ---- CSR build over edge_dst
__global__ void csr_hist(const int* __restrict__ edst, int* __restrict__ cnt) {
    int e = blockIdx.x * blockDim.x + threadIdx.x;
    if (e < N_EDGES) atomicAdd(&cnt[edst[e]], 1);
}

__global__ __launch_bounds__(1024) void csr_scan(const int* __restrict__ cnt,
                                                 int* __restrict__ off, int* __restrict__ pos) {
    __shared__ int sums[1024];
    const int tid = threadIdx.x;
    const int lo = tid * 98;
    const int hi = min(lo + 98, N_ATOMS);
    int s = 0;
    for (int i = lo; i < hi; ++i) s += cnt[i];
    sums[tid] = s;
    __syncthreads();
    for (int d = 1; d < 1024; d <<= 1) {
        int v = (tid >= d) ? sums[tid - d] : 0;
        __syncthreads();
        sums[tid] += v;
        __syncthreads();
    }
    int run = sums[tid] - s;  // exclusive base
    for (int i = lo; i < hi; ++i) { off[i] = run; pos[i] = run; run += cnt[i]; }
    if (tid == 1023) off[N_ATOMS] = run;
}

__global__ void csr_scatter(const int* __restrict__ edst, int* __restrict__ pos,
                            int* __restrict__ eid) {
    int e = blockIdx.x * blockDim.x + threadIdx.x;
    if (e < N_EDGES) {
        int idx = atomicAdd(&pos[edst[e]], 1);
        eid[idx] = e;
    }
}

// ---- node message sum via CSR gather -> block-scaled int8
__global__ __launch_bounds__(512) void seg_csr(
    const f16* __restrict__ H, const int* __restrict__ off, const int* __restrict__ eid,
    unsigned int* __restrict__ MnQ32, float* __restrict__ Msc)
{
    const int n = blockIdx.x * 8 + (threadIdx.x >> 6);
    const int lane = threadIdx.x & 63;
    const int j0 = off[n], j1 = off[n + 1];
    float acc[8];
    #pragma unroll
    for (int k = 0; k < 8; ++k) acc[k] = 0.f;
    for (int j = j0; j < j1; ++j) {
        const int e = eid[j];
        const half8 h = *reinterpret_cast<const half8*>(&H[e * D_H + lane * 8]);
        #pragma unroll
        for (int k = 0; k < 8; ++k) acc[k] += (float)h[k];
    }
    float m = 0.f;
    #pragma unroll
    for (int k = 0; k < 8; ++k) m = fmaxf(m, fabsf(acc[k]));
    m = fmaxf(m, __shfl_xor(m, 1));
    m = fmaxf(m, __shfl_xor(m, 2));
    m = fmaxf(m, 1e-20f);
    const float s = m * (1.f / 127.f);
    const float inv_s = 127.f / m;
    if ((lane & 3) == 0) Msc[n * 16 + (lane >> 2)] = s;
    int q[8];
    #pragma unroll
    for (int k = 0; k < 8; ++k) q[k] = __float2int_rn(acc[k] * inv_s);
    uint2 o;
    o.x = (q[0] & 0xff) | ((q[1] & 0xff) << 8) | ((q[2] & 0xff) << 16) | ((unsigned)(q[3] & 0xff) << 24);
    o.y = (q[4] & 0xff) | ((q[5] & 0xff) << 8) | ((q[6] & 0xff) << 16) | ((unsigned)(q[7] & 0xff) << 24);
    *reinterpret_cast<uint2*>(&MnQ32[n * 128 + lane * 2]) = o;
}

// ---- fused message-passing GEMM (in-place on Ha)
__global__ __launch_bounds__(512) void gemm_pass(
    const float* __restrict__ V, const float* __restrict__ E,
    const int* __restrict__ esrc, const char* __restrict__ MnQ,
    const float* __restrict__ Msc,
    f16* __restrict__ Ha, const f16* __restrict__ Wt, int ks_begin)
{
    __shared__ __align__(16) f16 Al[64 * LDA];
    const int tid = threadIdx.x;
    const int rowblk = blockIdx.x << 6;
    const int srow = tid >> 3;
    const int skk  = (tid & 7) << 2;
    const int e_s  = rowblk + srow;
    const int sv   = esrc[e_s];
    const int rev  = e_s ^ 1;
    const int lane = tid & 63;
    const int quad = lane >> 4;
    const int m16  = lane & 15;
    const int colbase = (tid >> 6) << 6;

    f32x4 acc[4][4];
    #pragma unroll
    for (int a = 0; a < 4; ++a)
    #pragma unroll
    for (int b = 0; b < 4; ++b)
    #pragma unroll
    for (int r = 0; r < 4; ++r) acc[a][b][r] = 0.f;

    for (int ks = ks_begin; ks < KC / 32; ++ks) {
        const int k0 = ks << 5;
        __syncthreads();
        {
            half4v w;
            if (k0 < D_H) {
                const char4 qc = *reinterpret_cast<const char4*>(&MnQ[sv * D_H + k0 + skk]);
                const float s = Msc[sv * 16 + ((k0 + skk) >> 5)];
                const half4v h4 = *reinterpret_cast<const half4v*>(&Ha[rev * D_H + k0 + skk]);
                w[0] = (f16)((float)qc.x * s - (float)h4[0]);
                w[1] = (f16)((float)qc.y * s - (float)h4[1]);
                w[2] = (f16)((float)qc.z * s - (float)h4[2]);
                w[3] = (f16)((float)qc.w * s - (float)h4[3]);
            } else {
                #pragma unroll
                for (int j = 0; j < 4; ++j) {
                    const int kk = k0 + skk + j - D_H;
                    float x = 0.f;
                    if (kk < D_V) x = V[sv * D_V + kk];
                    else if (kk < D_V + D_E) x = E[e_s * D_E + (kk - D_V)];
                    w[j] = (f16)x;
                }
            }
            *reinterpret_cast<half4v*>(&Al[srow * LDA + skk]) = w;
        }
        __syncthreads();
        half8 af[4];
        #pragma unroll
        for (int rt = 0; rt < 4; ++rt)
            af[rt] = *reinterpret_cast<const half8*>(&Al[(rt * 16 + m16) * LDA + quad * 8]);
        #pragma unroll
        for (int ct = 0; ct < 4; ++ct) {
            const int n = colbase + ct * 16 + m16;
            const half8 bf = *reinterpret_cast<const half8*>(&Wt[n * KC + k0 + quad * 8]);
            #pragma unroll
            for (int rt = 0; rt < 4; ++rt)
                acc[rt][ct] = __builtin_amdgcn_mfma_f32_16x16x32_f16(af[rt], bf, acc[rt][ct], 0, 0, 0);
        }
    }
    #pragma unroll
    for (int rt = 0; rt < 4; ++rt)
    #pragma unroll
    for (int ct = 0; ct < 4; ++ct)
    #pragma unroll
    for (int r = 0; r < 4; ++r) {
        const int row = rowblk + rt * 16 + quad * 4 + r;
        const int col = colbase + ct * 16 + m16;
        Ha[row * D_H + col] = (f16)fmaxf(acc[rt][ct][r], 0.f);
    }
}

// ---- output GEMM: h = relu([deq(Mn)(512); V(133)] @ WtO + b_o)
//      then per-block LDS molecule reduction (batch is sorted), one global atomic
//      row per distinct molecule in the block (fallback to direct atomics if >MAXML).
__global__ __launch_bounds__(512) void gemm_out(
    const float* __restrict__ V, const char* __restrict__ MnQ,
    const float* __restrict__ Msc,
    const int* __restrict__ batch, const float* __restrict__ bo,
    const f16* __restrict__ Wt, float* __restrict__ molsum)
{
    __shared__ __align__(16) f16 Al[64 * LDA];
    __shared__ float Ml[MAXML * D_H];
    __shared__ int batch_s[64];
    __shared__ float bo_s[D_H];
    const int tid = threadIdx.x;
    const int rowblk = blockIdx.x << 6;
    if (tid < 64) batch_s[tid] = batch[min(rowblk + tid, N_ATOMS - 1)];
    bo_s[tid] = bo[tid];
    #pragma unroll
    for (int j = 0; j < MAXML; ++j) Ml[j * 512 + tid] = 0.f;
    const int srow = tid >> 3;
    const int skk  = (tid & 7) << 2;
    const int arow = min(rowblk + srow, N_ATOMS - 1);
    const int lane = tid & 63;
    const int quad = lane >> 4;
    const int m16  = lane & 15;
    const int colbase = (tid >> 6) << 6;

    f32x4 acc[4][4];
    #pragma unroll
    for (int a = 0; a < 4; ++a)
    #pragma unroll
    for (int b = 0; b < 4; ++b)
    #pragma unroll
    for (int r = 0; r < 4; ++r) acc[a][b][r] = 0.f;

    for (int ks = 0; ks < KC / 32; ++ks) {
        const int k0 = ks << 5;
        __syncthreads();
        {
            half4v w;
            if (k0 < D_H) {
                const char4 qc = *reinterpret_cast<const char4*>(&MnQ[arow * D_H + k0 + skk]);
                const float s = Msc[arow * 16 + ((k0 + skk) >> 5)];
                w[0] = (f16)((float)qc.x * s);
                w[1] = (f16)((float)qc.y * s);
                w[2] = (f16)((float)qc.z * s);
                w[3] = (f16)((float)qc.w * s);
            } else {
                #pragma unroll
                for (int j = 0; j < 4; ++j) {
                    const int kk = k0 + skk + j - D_H;
                    w[j] = (kk < D_V) ? (f16)V[arow * D_V + kk] : (f16)0.f;
                }
            }
            *reinterpret_cast<half4v*>(&Al[srow * LDA + skk]) = w;
        }
        __syncthreads();
        half8 af[4];
        #pragma unroll
        for (int rt = 0; rt < 4; ++rt)
            af[rt] = *reinterpret_cast<const half8*>(&Al[(rt * 16 + m16) * LDA + quad * 8]);
        #pragma unroll
        for (int ct = 0; ct < 4; ++ct) {
            const int n = colbase + ct * 16 + m16;
            const half8 bf = *reinterpret_cast<const half8*>(&Wt[n * KC + k0 + quad * 8]);
            #pragma unroll
            for (int rt = 0; rt < 4; ++rt)
                acc[rt][ct] = __builtin_amdgcn_mfma_f32_16x16x32_f16(af[rt], bf, acc[rt][ct], 0, 0, 0);
        }
    }

    const int mol0 = batch_s[0];
    const int nmol = batch_s[63] - mol0 + 1;  // block-uniform
    if (nmol <= MAXML) {
        #pragma unroll
        for (int rt = 0; rt < 4; ++rt)
        #pragma unroll
        for (int ct = 0; ct < 4; ++ct)
        #pragma unroll
        for (int r = 0; r < 4; ++r) {
            const int row = rowblk + rt * 16 + quad * 4 + r;
            if (row < N_ATOMS) {
                const int col = colbase + ct * 16 + m16;
                const float x = fmaxf(acc[rt][ct][r] + bo_s[col], 0.f);
                atomicAdd(&Ml[(batch_s[rt * 16 + quad * 4 + r] - mol0) * 512 + col], x);
            }
        }
        __syncthreads();
        const int w = tid >> 6;  // wave id -> local molecule
        if (w < nmol) {
            #pragma unroll
            for (int j = 0; j < 8; ++j) {
                const int col = lane + j * 64;
                const float v = Ml[w * 512 + col];
                unsafeAtomicAdd(&molsum[(mol0 + w) * D_H + col], v);
            }
        }
    } else {  // rare fallback: direct global atomics
        #pragma unroll
        for (int rt = 0; rt < 4; ++rt)
        #pragma unroll
        for (int ct = 0; ct < 4; ++ct)
        #pragma unroll
        for (int r = 0; r < 4; ++r) {
            const int row = rowblk + rt * 16 + quad * 4 + r;
            if (row < N_ATOMS) {
                const int col = colbase + ct * 16 + m16;
                const float x = fmaxf(acc[rt][ct][r] + bo_s[col], 0.f);
                unsafeAtomicAdd(&molsum[batch_s[rt * 16 + quad * 4 + r] * D_H + col], x);
            }
        }
    }
}

__global__ void mol_count(const int* __restrict__ batch, float* __restrict__ cnt) {
    int a = blockIdx.x * blockDim.x + threadIdx.x;
    if (a < N_ATOMS) unsafeAtomicAdd(&cnt[batch[a]], 1.f);
}

__global__ __launch_bounds__(256) void bn_stats(
    const float* __restrict__ molsum, const float* __restrict__ cnt,
    const float* __restrict__ gamma, const float* __restrict__ beta,
    float* __restrict__ An, float* __restrict__ Bn)
{
    const int n = blockIdx.x;
    const int tid = threadIdx.x;
    float s = 0.f, s2 = 0.f;
    for (int m = tid; m < N_MOLS; m += 256) {
        float h = molsum[m * D_H + n] / fmaxf(cnt[m], 1.f);
        s += h; s2 += h * h;
    }
    for (int off = 32; off > 0; off >>= 1) {
        s  += __shfl_down(s, off);
        s2 += __shfl_down(s2, off);
    }
    __shared__ float sh[8];
    const int wave = tid >> 6, lane = tid & 63;
    if (lane == 0) { sh[wave] = s; sh[4 + wave] = s2; }
    __syncthreads();
    if (tid == 0) {
        float S  = sh[0] + sh[1] + sh[2] + sh[3];
        float S2 = sh[4] + sh[5] + sh[6] + sh[7];
        float mu = S / (float)N_MOLS;
        float var = fmaxf(S2 / (float)N_MOLS - mu * mu, 0.f);
        float sc = rsqrtf(var + 1e-5f) * gamma[n];
        An[n] = sc;
        Bn[n] = beta[n] - mu * sc;
    }
}

// in-place: out[gid] depends only on molsum[gid] (same index), An/Bn
__global__ void bn_apply(const float* __restrict__ molsum, const float* __restrict__ cnt,
                         const float* __restrict__ An, const float* __restrict__ Bn,
                         float* __restrict__ out)
{
    int gid = blockIdx.x * blockDim.x + threadIdx.x;
    int m = gid >> 9, n = gid & 511;
    float h = molsum[gid] / fmaxf(cnt[m], 1.f);
    out[gid] = h * An[n] + Bn[n];
}

extern "C" void kernel_launch(void* const* d_in, const int* in_sizes, int n_in,
                              void* d_out, int out_size, void* d_ws, size_t ws_size,
                              hipStream_t stream)
{
    (void)in_sizes; (void)n_in; (void)out_size; (void)ws_size;
    const float* V     = (const float*)d_in[0];
    const float* E     = (const float*)d_in[1];
    const int*   esrc  = (const int*)d_in[2];
    const int*   edst  = (const int*)d_in[3];
    const int*   batch = (const int*)d_in[4];
    const float* Wi    = (const float*)d_in[5];
    const float* Wh    = (const float*)d_in[6];
    const float* Wo    = (const float*)d_in[7];
    const float* bo    = (const float*)d_in[8];
    const float* gam   = (const float*)d_in[9];
    const float* bet   = (const float*)d_in[10];
    float* out = (float*)d_out;

    // workspace layout — total 265,396,864 B (~253.1 MiB)
    char* ws = (char*)d_ws;
    f16*   WtC  = (f16*)(ws + 0);                   //    688,128 B
    f16*   WtO  = (f16*)(ws + 688128);              //    688,128 B
    int*   off  = (int*)(ws + 1376256);             //    400,128 B (N_ATOMS+1 ints)
    int*   eid  = (int*)(ws + 1776384);             //    800,000 B
    int*   cnt  = (int*)(ws + 2576384);             //    400,000 B (also 'pos' cursor)
    float* Mc   = (float*)(ws + 2976384);           //     16,384 B
    float* An   = (float*)(ws + 2992768);           //      2,048 B
    float* Bn   = (float*)(ws + 2994816);           //      2,048 B
    f16*   Ha   = (f16*)(ws + 2996864);             // 204,800,000 B
    char*  MnQ  = (char*)(ws + 207796864);          //  51,200,000 B int8
    float* Msc  = (float*)(ws + 258996864);         //   6,400,000 B scales
    unsigned int* MnQ32 = (unsigned int*)MnQ;
    float* Ms = out;                                 // mol sums live in d_out (8,388,608 B)

    // weights
    wt_build<<<(D_H * KC + 255) / 256, 256, 0, stream>>>(Wh, D_H, Wi, D_V + D_E, WtC);
    wt_build<<<(D_H * KC + 255) / 256, 256, 0, stream>>>(Wo + D_V * D_H, D_H, Wo, D_V, WtO);

    // CSR over edge_dst (cnt doubles as scatter cursor 'pos')
    hipMemsetAsync(cnt, 0, 400000, stream);
    csr_hist<<<(N_EDGES + 511) / 512, 512, 0, stream>>>(edst, cnt);
    csr_scan<<<1, 1024, 0, stream>>>(cnt, off, cnt);
    csr_scatter<<<(N_EDGES + 511) / 512, 512, 0, stream>>>(edst, cnt, eid);

    // init: H = relu([V;E] @ W_i)
    gemm_pass<<<N_EDGES / 64, 512, 0, stream>>>(V, E, esrc, MnQ, Msc, Ha, WtC, 16);

    // DEPTH-1 = 2 message-passing iterations (int8 block-scaled Mn)
    for (int it = 0; it < 2; ++it) {
        seg_csr<<<N_ATOMS / 8, 512, 0, stream>>>(Ha, off, eid, MnQ32, Msc);
        gemm_pass<<<N_EDGES / 64, 512, 0, stream>>>(V, E, esrc, MnQ, Msc, Ha, WtC, 0);
    }

    // final edge->node aggregation (same int8 path; gemm_out reads it coalesced)
    seg_csr<<<N_ATOMS / 8, 512, 0, stream>>>(Ha, off, eid, MnQ32, Msc);

    // output GEMM with fused LDS-reduced mol-sum (into d_out), then BatchNorm
    hipMemsetAsync(Ms, 0, (size_t)N_MOLS * D_H * 4, stream);
    hipMemsetAsync(Mc, 0, 16384, stream);
    mol_count<<<(N_ATOMS + 255) / 256, 256, 0, stream>>>(batch, Mc);
    gemm_out<<<(N_ATOMS + 63) / 64, 512, 0, stream>>>(V, MnQ, Msc, batch, bo, WtO, Ms);

    bn_stats<<<D_H, 256, 0, stream>>>(Ms, Mc, gam, bet, An, Bn);
    bn_apply<<<(N_MOLS * D_H) / 256, 256, 0, stream>>>(Ms, Mc, An, Bn, out);
}

// Round 7
// 1588.269 us; speedup vs baseline: 1.3142x; 1.1814x over previous
//
#include <hip/hip_runtime.h>

typedef _Float16 f16;
typedef _Float16 half8 __attribute__((ext_vector_type(8)));
typedef _Float16 half4v __attribute__((ext_vector_type(4)));
typedef float f32x4 __attribute__((ext_vector_type(4)));

#define N_ATOMS 100000
#define N_EDGES 200000
#define N_MOLS  4096
#define D_V 133
#define D_E 14
#define D_H 512
#define KC  672        // padded K for [W_h(512); W_i(147)] and [W_o_m(512); W_o_v(133)]
#define LDA 40         // LDS A-tile row stride (f16 elems): 80 B rows

// ---- weight build: Wt[n][k] f16 transposed, from stacked f32 W1[r1][512], W2[r2][512]
__global__ void wt_build(const float* __restrict__ W1, int r1,
                         const float* __restrict__ W2, int r2,
                         f16* __restrict__ Wt) {
    int gid = blockIdx.x * blockDim.x + threadIdx.x;
    if (gid >= D_H * KC) return;
    int n = gid / KC;
    int k = gid - n * KC;
    float x = 0.f;
    if (k < r1) x = W1[k * D_H + n];
    else if (k < r1 + r2) x = W2[(k - r1) * D_H + n];
    Wt[gid] = (f16)x;
}

// ---- CSR build over edge_dst
__global__ void csr_hist(const int* __restrict__ edst, int* __restrict__ cnt) {
    int e = blockIdx.x * blockDim.x + threadIdx.x;
    if (e < N_EDGES) atomicAdd(&cnt[edst[e]], 1);
}

__global__ __launch_bounds__(1024) void csr_scan(const int* __restrict__ cnt,
                                                 int* __restrict__ off, int* __restrict__ pos) {
    __shared__ int sums[1024];
    const int tid = threadIdx.x;
    const int lo = tid * 98;
    const int hi = min(lo + 98, N_ATOMS);
    int s = 0;
    for (int i = lo; i < hi; ++i) s += cnt[i];
    sums[tid] = s;
    __syncthreads();
    for (int d = 1; d < 1024; d <<= 1) {
        int v = (tid >= d) ? sums[tid - d] : 0;
        __syncthreads();
        sums[tid] += v;
        __syncthreads();
    }
    int run = sums[tid] - s;  // exclusive base
    for (int i = lo; i < hi; ++i) { off[i] = run; pos[i] = run; run += cnt[i]; }
    if (tid == 1023) off[N_ATOMS] = run;
}

__global__ void csr_scatter(const int* __restrict__ edst, int* __restrict__ pos,
                            int* __restrict__ eid) {
    int e = blockIdx.x * blockDim.x + threadIdx.x;
    if (e < N_EDGES) {
        int idx = atomicAdd(&pos[edst[e]], 1);
        eid[idx] = e;
    }
}

// ---- node message sum via CSR gather -> block-scaled int8
__global__ __launch_bounds__(512) void seg_csr(
    const f16* __restrict__ H, const int* __restrict__ off, const int* __restrict__ eid,
    unsigned int* __restrict__ MnQ32, float* __restrict__ Msc)
{
    const int n = blockIdx.x * 8 + (threadIdx.x >> 6);
    const int lane = threadIdx.x & 63;
    const int j0 = off[n], j1 = off[n + 1];
    float acc[8];
    #pragma unroll
    for (int k = 0; k < 8; ++k) acc[k] = 0.f;
    for (int j = j0; j < j1; ++j) {
        const int e = eid[j];
        const half8 h = *reinterpret_cast<const half8*>(&H[e * D_H + lane * 8]);
        #pragma unroll
        for (int k = 0; k < 8; ++k) acc[k] += (float)h[k];
    }
    float m = 0.f;
    #pragma unroll
    for (int k = 0; k < 8; ++k) m = fmaxf(m, fabsf(acc[k]));
    m = fmaxf(m, __shfl_xor(m, 1));
    m = fmaxf(m, __shfl_xor(m, 2));
    m = fmaxf(m, 1e-20f);
    const float s = m * (1.f / 127.f);
    const float inv_s = 127.f / m;
    if ((lane & 3) == 0) Msc[n * 16 + (lane >> 2)] = s;
    int q[8];
    #pragma unroll
    for (int k = 0; k < 8; ++k) q[k] = __float2int_rn(acc[k] * inv_s);
    uint2 o;
    o.x = (q[0] & 0xff) | ((q[1] & 0xff) << 8) | ((q[2] & 0xff) << 16) | ((unsigned)(q[3] & 0xff) << 24);
    o.y = (q[4] & 0xff) | ((q[5] & 0xff) << 8) | ((q[6] & 0xff) << 16) | ((unsigned)(q[7] & 0xff) << 24);
    *reinterpret_cast<uint2*>(&MnQ32[n * 128 + lane * 2]) = o;
}

// ---- fused message-passing GEMM (in-place on Ha), 1-deep register prefetch
__global__ __launch_bounds__(512) void gemm_pass(
    const float* __restrict__ V, const float* __restrict__ E,
    const int* __restrict__ esrc, const char* __restrict__ MnQ,
    const float* __restrict__ Msc,
    f16* __restrict__ Ha, const f16* __restrict__ Wt, int ks_begin)
{
    __shared__ __align__(16) f16 Al[64 * LDA];
    const int tid = threadIdx.x;
    const int rowblk = blockIdx.x << 6;
    const int srow = tid >> 3;
    const int skk  = (tid & 7) << 2;
    const int e_s  = rowblk + srow;
    const int sv   = esrc[e_s];
    const int rev  = e_s ^ 1;
    const int lane = tid & 63;
    const int quad = lane >> 4;
    const int m16  = lane & 15;
    const int colbase = (tid >> 6) << 6;

    f32x4 acc[4][4];
    #pragma unroll
    for (int a = 0; a < 4; ++a)
    #pragma unroll
    for (int b = 0; b < 4; ++b)
    #pragma unroll
    for (int r = 0; r < 4; ++r) acc[a][b][r] = 0.f;

    // prefetch registers
    char4 pq; float ps; half4v ph; float pv[4];
    auto issue = [&](int ks) {
        const int k0 = ks << 5;
        if (k0 < D_H) {
            pq = *reinterpret_cast<const char4*>(&MnQ[sv * D_H + k0 + skk]);
            ps = Msc[sv * 16 + (k0 >> 5)];
            ph = *reinterpret_cast<const half4v*>(&Ha[rev * D_H + k0 + skk]);
        } else {
            #pragma unroll
            for (int j = 0; j < 4; ++j) {
                const int kk = k0 + skk + j - D_H;
                float x = 0.f;
                if (kk < D_V) x = V[sv * D_V + kk];
                else if (kk < D_V + D_E) x = E[e_s * D_E + (kk - D_V)];
                pv[j] = x;
            }
        }
    };

    issue(ks_begin);
    for (int ks = ks_begin; ks < KC / 32; ++ks) {
        const int k0 = ks << 5;
        half4v w;
        if (k0 < D_H) {
            w[0] = (f16)((float)pq.x * ps - (float)ph[0]);
            w[1] = (f16)((float)pq.y * ps - (float)ph[1]);
            w[2] = (f16)((float)pq.z * ps - (float)ph[2]);
            w[3] = (f16)((float)pq.w * ps - (float)ph[3]);
        } else {
            w[0] = (f16)pv[0]; w[1] = (f16)pv[1]; w[2] = (f16)pv[2]; w[3] = (f16)pv[3];
        }
        __syncthreads();
        *reinterpret_cast<half4v*>(&Al[srow * LDA + skk]) = w;
        __syncthreads();
        if (ks + 1 < KC / 32) issue(ks + 1);  // overlap with MFMA below
        half8 af[4];
        #pragma unroll
        for (int rt = 0; rt < 4; ++rt)
            af[rt] = *reinterpret_cast<const half8*>(&Al[(rt * 16 + m16) * LDA + quad * 8]);
        #pragma unroll
        for (int ct = 0; ct < 4; ++ct) {
            const int n = colbase + ct * 16 + m16;
            const half8 bf = *reinterpret_cast<const half8*>(&Wt[n * KC + k0 + quad * 8]);
            #pragma unroll
            for (int rt = 0; rt < 4; ++rt)
                acc[rt][ct] = __builtin_amdgcn_mfma_f32_16x16x32_f16(af[rt], bf, acc[rt][ct], 0, 0, 0);
        }
    }
    // epilogue: in-place overwrite is safe (all Ha[rev] reads are in-block, barrier-ordered)
    #pragma unroll
    for (int rt = 0; rt < 4; ++rt)
    #pragma unroll
    for (int ct = 0; ct < 4; ++ct)
    #pragma unroll
    for (int r = 0; r < 4; ++r) {
        const int row = rowblk + rt * 16 + quad * 4 + r;
        const int col = colbase + ct * 16 + m16;
        Ha[row * D_H + col] = (f16)fmaxf(acc[rt][ct][r], 0.f);
    }
}

// ---- output GEMM: Hv[a] = relu([deq(Mn)(512); V(133)] @ WtO + b_o)  (plain store, f16)
__global__ __launch_bounds__(512) void gemm_out(
    const float* __restrict__ V, const char* __restrict__ MnQ,
    const float* __restrict__ Msc, const float* __restrict__ bo,
    const f16* __restrict__ Wt, f16* __restrict__ Hv)
{
    __shared__ __align__(16) f16 Al[64 * LDA];
    __shared__ float bo_s[D_H];
    const int tid = threadIdx.x;
    const int rowblk = blockIdx.x << 6;
    bo_s[tid] = bo[tid];
    const int srow = tid >> 3;
    const int skk  = (tid & 7) << 2;
    const int arow = min(rowblk + srow, N_ATOMS - 1);
    const int lane = tid & 63;
    const int quad = lane >> 4;
    const int m16  = lane & 15;
    const int colbase = (tid >> 6) << 6;

    f32x4 acc[4][4];
    #pragma unroll
    for (int a = 0; a < 4; ++a)
    #pragma unroll
    for (int b = 0; b < 4; ++b)
    #pragma unroll
    for (int r = 0; r < 4; ++r) acc[a][b][r] = 0.f;

    char4 pq; float ps; float pv[4];
    auto issue = [&](int ks) {
        const int k0 = ks << 5;
        if (k0 < D_H) {
            pq = *reinterpret_cast<const char4*>(&MnQ[arow * D_H + k0 + skk]);
            ps = Msc[arow * 16 + (k0 >> 5)];
        } else {
            #pragma unroll
            for (int j = 0; j < 4; ++j) {
                const int kk = k0 + skk + j - D_H;
                pv[j] = (kk < D_V) ? V[arow * D_V + kk] : 0.f;
            }
        }
    };

    issue(0);
    for (int ks = 0; ks < KC / 32; ++ks) {
        const int k0 = ks << 5;
        half4v w;
        if (k0 < D_H) {
            w[0] = (f16)((float)pq.x * ps);
            w[1] = (f16)((float)pq.y * ps);
            w[2] = (f16)((float)pq.z * ps);
            w[3] = (f16)((float)pq.w * ps);
        } else {
            w[0] = (f16)pv[0]; w[1] = (f16)pv[1]; w[2] = (f16)pv[2]; w[3] = (f16)pv[3];
        }
        __syncthreads();
        *reinterpret_cast<half4v*>(&Al[srow * LDA + skk]) = w;
        __syncthreads();
        if (ks + 1 < KC / 32) issue(ks + 1);
        half8 af[4];
        #pragma unroll
        for (int rt = 0; rt < 4; ++rt)
            af[rt] = *reinterpret_cast<const half8*>(&Al[(rt * 16 + m16) * LDA + quad * 8]);
        #pragma unroll
        for (int ct = 0; ct < 4; ++ct) {
            const int n = colbase + ct * 16 + m16;
            const half8 bf = *reinterpret_cast<const half8*>(&Wt[n * KC + k0 + quad * 8]);
            #pragma unroll
            for (int rt = 0; rt < 4; ++rt)
                acc[rt][ct] = __builtin_amdgcn_mfma_f32_16x16x32_f16(af[rt], bf, acc[rt][ct], 0, 0, 0);
        }
    }
    #pragma unroll
    for (int rt = 0; rt < 4; ++rt)
    #pragma unroll
    for (int ct = 0; ct < 4; ++ct)
    #pragma unroll
    for (int r = 0; r < 4; ++r) {
        const int row = rowblk + rt * 16 + quad * 4 + r;
        if (row < N_ATOMS) {
            const int col = colbase + ct * 16 + m16;
            Hv[row * D_H + col] = (f16)fmaxf(acc[rt][ct][r] + bo_s[col], 0.f);
        }
    }
}

// ---- molecule mean: batch sorted -> contiguous atom range per mol (binary search)
__global__ __launch_bounds__(512) void mol_mean(
    const f16* __restrict__ Hv, const int* __restrict__ batch, float* __restrict__ mean)
{
    const int m = blockIdx.x;
    __shared__ int sh[2];
    if (threadIdx.x == 0) {
        int lo = 0, hi = N_ATOMS;
        while (lo < hi) { int mid = (lo + hi) >> 1; if (batch[mid] < m) lo = mid + 1; else hi = mid; }
        sh[0] = lo;
        int lo2 = lo; hi = N_ATOMS;
        while (lo2 < hi) { int mid = (lo2 + hi) >> 1; if (batch[mid] < m + 1) lo2 = mid + 1; else hi = mid; }
        sh[1] = lo2;
    }
    __syncthreads();
    const int a0 = sh[0], a1 = sh[1];
    float acc = 0.f;
    for (int a = a0; a < a1; ++a) acc += (float)Hv[(size_t)a * D_H + threadIdx.x];
    mean[m * D_H + threadIdx.x] = acc / (float)max(a1 - a0, 1);
}

__global__ __launch_bounds__(256) void bn_stats(
    const float* __restrict__ mean_in, const float* __restrict__ gamma,
    const float* __restrict__ beta, float* __restrict__ An, float* __restrict__ Bn)
{
    const int n = blockIdx.x;
    const int tid = threadIdx.x;
    float s = 0.f, s2 = 0.f;
    for (int m = tid; m < N_MOLS; m += 256) {
        float h = mean_in[m * D_H + n];
        s += h; s2 += h * h;
    }
    for (int off = 32; off > 0; off >>= 1) {
        s  += __shfl_down(s, off);
        s2 += __shfl_down(s2, off);
    }
    __shared__ float sh[8];
    const int wave = tid >> 6, lane = tid & 63;
    if (lane == 0) { sh[wave] = s; sh[4 + wave] = s2; }
    __syncthreads();
    if (tid == 0) {
        float S  = sh[0] + sh[1] + sh[2] + sh[3];
        float S2 = sh[4] + sh[5] + sh[6] + sh[7];
        float mu = S / (float)N_MOLS;
        float var = fmaxf(S2 / (float)N_MOLS - mu * mu, 0.f);
        float sc = rsqrtf(var + 1e-5f) * gamma[n];
        An[n] = sc;
        Bn[n] = beta[n] - mu * sc;
    }
}

// in-place: out[gid] depends only on mean[gid] (same index), An/Bn
__global__ void bn_apply(const float* __restrict__ mean_in,
                         const float* __restrict__ An, const float* __restrict__ Bn,
                         float* __restrict__ out)
{
    int gid = blockIdx.x * blockDim.x + threadIdx.x;
    int n = gid & 511;
    out[gid] = mean_in[gid] * An[n] + Bn[n];
}

extern "C" void kernel_launch(void* const* d_in, const int* in_sizes, int n_in,
                              void* d_out, int out_size, void* d_ws, size_t ws_size,
                              hipStream_t stream)
{
    (void)in_sizes; (void)n_in; (void)out_size; (void)ws_size;
    const float* V     = (const float*)d_in[0];
    const float* E     = (const float*)d_in[1];
    const int*   esrc  = (const int*)d_in[2];
    const int*   edst  = (const int*)d_in[3];
    const int*   batch = (const int*)d_in[4];
    const float* Wi    = (const float*)d_in[5];
    const float* Wh    = (const float*)d_in[6];
    const float* Wo    = (const float*)d_in[7];
    const float* bo    = (const float*)d_in[8];
    const float* gam   = (const float*)d_in[9];
    const float* bet   = (const float*)d_in[10];
    float* out = (float*)d_out;

    // workspace layout — total 265,396,864 B (~253.1 MiB)
    char* ws = (char*)d_ws;
    f16*   WtC  = (f16*)(ws + 0);                   //    688,128 B
    f16*   WtO  = (f16*)(ws + 688128);              //    688,128 B
    int*   off  = (int*)(ws + 1376256);             //    400,128 B (N_ATOMS+1 ints)
    int*   eid  = (int*)(ws + 1776384);             //    800,000 B
    int*   cnt  = (int*)(ws + 2576384);             //    400,000 B (also 'pos' cursor)
    float* An   = (float*)(ws + 2992768);           //      2,048 B
    float* Bn   = (float*)(ws + 2994816);           //      2,048 B
    f16*   Ha   = (f16*)(ws + 2996864);             // 204,800,000 B (edge states; reused as Hv)
    char*  MnQ  = (char*)(ws + 207796864);          //  51,200,000 B int8
    float* Msc  = (float*)(ws + 258996864);         //   6,400,000 B scales
    unsigned int* MnQ32 = (unsigned int*)MnQ;
    f16*   Hv   = Ha;                                // Ha is dead after final seg_csr
    float* mean = out;                               // mol means live in d_out

    // weights
    wt_build<<<(D_H * KC + 255) / 256, 256, 0, stream>>>(Wh, D_H, Wi, D_V + D_E, WtC);
    wt_build<<<(D_H * KC + 255) / 256, 256, 0, stream>>>(Wo + D_V * D_H, D_H, Wo, D_V, WtO);

    // CSR over edge_dst (cnt doubles as scatter cursor 'pos')
    hipMemsetAsync(cnt, 0, 400000, stream);
    csr_hist<<<(N_EDGES + 511) / 512, 512, 0, stream>>>(edst, cnt);
    csr_scan<<<1, 1024, 0, stream>>>(cnt, off, cnt);
    csr_scatter<<<(N_EDGES + 511) / 512, 512, 0, stream>>>(edst, cnt, eid);

    // init: H = relu([V;E] @ W_i)
    gemm_pass<<<N_EDGES / 64, 512, 0, stream>>>(V, E, esrc, MnQ, Msc, Ha, WtC, 16);

    // DEPTH-1 = 2 message-passing iterations (int8 block-scaled Mn)
    for (int it = 0; it < 2; ++it) {
        seg_csr<<<N_ATOMS / 8, 512, 0, stream>>>(Ha, off, eid, MnQ32, Msc);
        gemm_pass<<<N_EDGES / 64, 512, 0, stream>>>(V, E, esrc, MnQ, Msc, Ha, WtC, 0);
    }

    // final edge->node aggregation
    seg_csr<<<N_ATOMS / 8, 512, 0, stream>>>(Ha, off, eid, MnQ32, Msc);

    // output GEMM -> Hv (reuses Ha), then mol means + BatchNorm
    gemm_out<<<(N_ATOMS + 63) / 64, 512, 0, stream>>>(V, MnQ, Msc, bo, WtO, Hv);
    mol_mean<<<N_MOLS, 512, 0, stream>>>(Hv, batch, mean);
    bn_stats<<<D_H, 256, 0, stream>>>(mean, gam, bet, An, Bn);
    bn_apply<<<(N_MOLS * D_H) / 256, 256, 0, stream>>>(mean, An, Bn, out);
}